// Round 1
// baseline (27.191 us; speedup 1.0000x reference)
//
#include <hip/hip_runtime.h>

// HardUpsampling: seqs [N=16, T=2048, M=256] f32, durations [N, T] i32 in [0,4)
// out = concat( upsampled [N, L, M] f32 , lens [N] (written as f32) )
// L = (out_size - N) / (N*M), known host-side from out_size.

#define N_ROWS 16
#define T_LEN  2048
#define M_DIM  256
#define M_VEC  (M_DIM / 4)   // 64 float4 per row

// ---------------- Kernel 1: per-row cumsum + lens ----------------
// grid = N_ROWS blocks, block = 64 (one wave). Lane l scans 32 contiguous
// durations, then wave-inclusive-scan of per-lane totals via shfl_up.
__global__ __launch_bounds__(64) void cumsum_kernel(
    const int* __restrict__ dur, int* __restrict__ cum,
    float* __restrict__ lens_out) {
  const int n = blockIdx.x;
  const int lane = threadIdx.x;            // 0..63
  const int CH = T_LEN / 64;               // 32 elements per lane
  const int base = n * T_LEN + lane * CH;

  int vals[CH];
  int tot = 0;
#pragma unroll
  for (int j = 0; j < CH; ++j) {
    tot += dur[base + j];
    vals[j] = tot;                         // local inclusive prefix
  }

  // wave-wide inclusive scan of per-lane totals (64 lanes)
  int scan = tot;
#pragma unroll
  for (int d = 1; d < 64; d <<= 1) {
    int v = __shfl_up(scan, d, 64);
    if (lane >= d) scan += v;
  }
  const int excl = scan - tot;             // exclusive prefix for this lane

#pragma unroll
  for (int j = 0; j < CH; ++j) cum[base + j] = excl + vals[j];

  if (lane == 63) lens_out[n] = (float)scan;   // scan at lane63 == row total
}

// ---------------- Kernel 2: gather/upsample ----------------
// One wave per output row (n, pos). 4 waves per 256-thread block.
// 64-ary two-round ballot search for idx = #{t : cum[t] <= pos}, then
// coalesced float4 row copy. Padded rows written as zeros.
__global__ __launch_bounds__(256) void gather_kernel(
    const float4* __restrict__ seqs4, const int* __restrict__ cum,
    float4* __restrict__ out4, int max_len) {
  const int lane = threadIdx.x & 63;
  const int wave = threadIdx.x >> 6;
  const int pos = blockIdx.x * 4 + wave;
  const int n = blockIdx.y;
  if (pos >= max_len) return;

  const int* __restrict__ c = cum + n * T_LEN;
  const int len = c[T_LEN - 1];

  float4 v;
  if (pos >= len) {
    v = make_float4(0.f, 0.f, 0.f, 0.f);
  } else {
    // round 1: lane l probes boundary of 32-chunk l
    const int b = c[lane * 32 + 31];
    const unsigned long long m1 = __ballot(b <= pos);
    const int k = __popcll(m1);            // first chunk whose boundary > pos
    // round 2: lanes 0..31 probe inside chunk k
    int flag = 0;
    if (lane < 32) flag = (c[k * 32 + lane] <= pos) ? 1 : 0;
    const unsigned long long m2 = __ballot(flag);
    const int idx = k * 32 + __popcll(m2); // == searchsorted(c, pos, 'right'), < T
    v = seqs4[(size_t)(n * T_LEN + idx) * M_VEC + lane];
  }
  out4[((size_t)n * max_len + pos) * M_VEC + lane] = v;
}

extern "C" void kernel_launch(void* const* d_in, const int* in_sizes, int n_in,
                              void* d_out, int out_size, void* d_ws, size_t ws_size,
                              hipStream_t stream) {
  const float* seqs = (const float*)d_in[0];       // [16, 2048, 256] f32
  const int* durations = (const int*)d_in[1];      // [16, 2048] i32
  float* out = (float*)d_out;

  const int N = N_ROWS;
  const int M = M_DIM;
  const int max_len = (out_size - N) / (N * M);    // padded output length L

  int* cum = (int*)d_ws;                           // N*T ints = 128 KiB scratch
  float* lens_out = out + (size_t)N * max_len * M; // lens chunk (as f32 values)

  cumsum_kernel<<<dim3(N), dim3(64), 0, stream>>>(durations, cum, lens_out);

  dim3 grid((max_len + 3) / 4, N);
  gather_kernel<<<grid, dim3(256), 0, stream>>>(
      (const float4*)seqs, cum, (float4*)out, max_len);
}

// Round 2
// 22.889 us; speedup vs baseline: 1.1880x; 1.1880x over previous
//
#include <hip/hip_runtime.h>

// HardUpsampling: seqs [N=16, T=2048, M=256] f32, durations [N, T] i32 in [0,4)
// out = concat( upsampled [N, L, M] f32 , lens [N] (written as f32) )
// L = (out_size - N) / (N*M), known host-side from out_size.
//
// Strategy (round 2): INVERTED mapping. Instead of each output slot searching
// for its source token (gather; caused ~3x HBM read amplification via
// cross-XCD L2 duplication), each SOURCE token reads its row once (fully
// streaming) and scatters it to its d consecutive output rows (each output
// row written exactly once, coalesced). Padding fused into the same kernel.

#define N_ROWS 16
#define T_LEN  2048
#define M_DIM  256
#define M_VEC  (M_DIM / 4)   // 64 float4 per row

// ---------------- Kernel 1: per-row inclusive cumsum + lens ----------------
// grid = N_ROWS blocks, block = 64 (one wave).
__global__ __launch_bounds__(64) void cumsum_kernel(
    const int* __restrict__ dur, int* __restrict__ cum,
    float* __restrict__ lens_out) {
  const int n = blockIdx.x;
  const int lane = threadIdx.x;            // 0..63
  const int CH = T_LEN / 64;               // 32 elements per lane
  const int base = n * T_LEN + lane * CH;

  int vals[CH];
  int tot = 0;
#pragma unroll
  for (int j = 0; j < CH; ++j) {
    tot += dur[base + j];
    vals[j] = tot;                         // local inclusive prefix
  }

  // wave-wide inclusive scan of per-lane totals
  int scan = tot;
#pragma unroll
  for (int d = 1; d < 64; d <<= 1) {
    int v = __shfl_up(scan, d, 64);
    if (lane >= d) scan += v;
  }
  const int excl = scan - tot;

#pragma unroll
  for (int j = 0; j < CH; ++j) cum[base + j] = excl + vals[j];

  if (lane == 63) lens_out[n] = (float)scan;
}

// ---------------- Kernel 2: scatter + pad ----------------
// One wave per index idx in [0, max(T, max_len)). 4 waves / 256-thr block.
//  - if idx < T: token scatter — read seqs row idx once, write to output rows
//    [cum[idx]-d, cum[idx]) (0..3 contiguous rows, each written exactly once).
//  - if idx >= len && idx < max_len: write a zero row (padding).
__global__ __launch_bounds__(256) void scatter_kernel(
    const float4* __restrict__ seqs4, const int* __restrict__ dur,
    const int* __restrict__ cum, float4* __restrict__ out4, int max_len) {
  const int lane = threadIdx.x & 63;
  const int wave = threadIdx.x >> 6;
  const int idx = blockIdx.x * 4 + wave;
  const int n = blockIdx.y;

  const int* __restrict__ c = cum + n * T_LEN;
  const int len = c[T_LEN - 1];            // wave-uniform broadcast load

  float4* __restrict__ orow = out4 + (size_t)n * max_len * M_VEC + lane;

  // ---- padding duty ----
  if (idx >= len && idx < max_len) {
    orow[(size_t)idx * M_VEC] = make_float4(0.f, 0.f, 0.f, 0.f);
  }

  // ---- scatter duty ----
  if (idx < T_LEN) {
    const int d = dur[n * T_LEN + idx];    // wave-uniform
    if (d > 0) {
      const int end = c[idx];              // inclusive cumsum
      const int start = end - d;
      const float4 v = seqs4[(size_t)(n * T_LEN + idx) * M_VEC + lane];
#pragma unroll 3
      for (int i = start; i < end; ++i) {
        orow[(size_t)i * M_VEC] = v;
      }
    }
  }
}

extern "C" void kernel_launch(void* const* d_in, const int* in_sizes, int n_in,
                              void* d_out, int out_size, void* d_ws, size_t ws_size,
                              hipStream_t stream) {
  const float* seqs = (const float*)d_in[0];       // [16, 2048, 256] f32
  const int* durations = (const int*)d_in[1];      // [16, 2048] i32
  float* out = (float*)d_out;

  const int N = N_ROWS;
  const int M = M_DIM;
  const int max_len = (out_size - N) / (N * M);    // padded output length L

  int* cum = (int*)d_ws;                           // N*T ints = 128 KiB scratch
  float* lens_out = out + (size_t)N * max_len * M; // lens chunk (as f32 values)

  cumsum_kernel<<<dim3(N), dim3(64), 0, stream>>>(durations, cum, lens_out);

  const int span = (max_len > T_LEN) ? max_len : T_LEN;
  dim3 grid((span + 3) / 4, N);
  scatter_kernel<<<grid, dim3(256), 0, stream>>>(
      (const float4*)seqs, durations, cum, (float4*)out, max_len);
}